// Round 4
// baseline (483.030 us; speedup 1.0000x reference)
//
#include <hip/hip_runtime.h>

// Problem constants (from reference)
#define B_  16
#define T_  2048
#define IN_ 512
#define H_  512
#define M_  (B_ * T_)

// GEMM tiling
#define BM 128
#define BN 128
#define BK 16
#define LDT (BM + 4)     // pad: staging stores 2-way (free), reads conflict-free

// Fused producer-consumer structure
#define NTAU   16        // T split into 16 chunks of 128
#define TCHUNK 128
#define GEMM_BLOCKS 1024 // 16 tau x 16 b x 4 n
#define SCAN_BLOCKS 32   // 8192 chains / 256
#define BLOCKS_PER_TAU 64

static __device__ __forceinline__ float4 ld4(const float* p) {
    return *reinterpret_cast<const float4*>(p);
}

// ---------------------------------------------------------------------------
// GEMM body: h[m][n] = sum_k x[m][k]*W[n][k] + b[n], fp32 VALU.
// k accumulated strictly in order 0..511 with fmaf -> bit-identical to np/BLAS
// sequential-k order (Round 2/3 empirically bit-match: absmax 0.0). DO NOT
// reorder the k loop.
// 8x8 micro-tile, 4+4 split (rows ty*4 & ty*4+64, cols tx*4 & tx*4+64):
// LDS reads are <=2-way bank-aliased (free) vs Round-3's 4-way on tx*8.
// Staging loads register-double-buffered: next tile's global loads issue
// right after the barrier and drain during the 16-k compute phase.
// ---------------------------------------------------------------------------
__device__ __forceinline__
void gemm_body(const float* __restrict__ X, const float* __restrict__ W,
               const float* __restrict__ bias, float* __restrict__ Hout,
               int gg, int* flags)
{
    __shared__ float As[BK][LDT];
    __shared__ float Bs[BK][LDT];

    const int tid = threadIdx.x;
    const int tau = gg >> 6;          // t-chunk this block produces
    const int idx = gg & 63;
    const int bb  = idx >> 2;         // batch index 0..15
    const int ni  = idx & 3;          // n-tile 0..3
    const int m0  = bb * 2048 + tau * TCHUNK;   // 128 rows = 128 consecutive t of batch bb
    const int n0  = ni * BN;

    const int tx = tid & 15;          // col group
    const int ty = tid >> 4;          // row group

    // staging: row = tid>>2 (0..63), kph = (tid&3)*4 -> 64B-coalesced global loads
    const int row = tid >> 2;
    const int kph = (tid & 3) * 4;

    const float* pa0 = X + (size_t)(m0 + row) * IN_ + kph;
    const float* pa1 = pa0 + (size_t)64 * IN_;
    const float* pb0 = W + (size_t)(n0 + row) * IN_ + kph;
    const float* pb1 = pb0 + (size_t)64 * IN_;

    float4 ra0 = ld4(pa0), ra1 = ld4(pa1), rb0 = ld4(pb0), rb1 = ld4(pb1);

    float acc[8][8];
#pragma unroll
    for (int i = 0; i < 8; ++i)
#pragma unroll
        for (int j = 0; j < 8; ++j) acc[i][j] = 0.0f;

    for (int k0 = 0; k0 < IN_; k0 += BK) {
        // write staged registers (tile k0) to LDS
        As[kph + 0][row]      = ra0.x;  As[kph + 1][row]      = ra0.y;
        As[kph + 2][row]      = ra0.z;  As[kph + 3][row]      = ra0.w;
        As[kph + 0][row + 64] = ra1.x;  As[kph + 1][row + 64] = ra1.y;
        As[kph + 2][row + 64] = ra1.z;  As[kph + 3][row + 64] = ra1.w;
        Bs[kph + 0][row]      = rb0.x;  Bs[kph + 1][row]      = rb0.y;
        Bs[kph + 2][row]      = rb0.z;  Bs[kph + 3][row]      = rb0.w;
        Bs[kph + 0][row + 64] = rb1.x;  Bs[kph + 1][row + 64] = rb1.y;
        Bs[kph + 2][row + 64] = rb1.z;  Bs[kph + 3][row + 64] = rb1.w;
        __syncthreads();

        // prefetch next tile into registers; vmcnt waited at next LDS write
        if (k0 + BK < IN_) {
            ra0 = ld4(pa0 + k0 + BK);  ra1 = ld4(pa1 + k0 + BK);
            rb0 = ld4(pb0 + k0 + BK);  rb1 = ld4(pb1 + k0 + BK);
        }

#pragma unroll
        for (int k = 0; k < BK; ++k) {
            float4 av0 = ld4(&As[k][ty * 4]);        // banks ty*4..+3: conflict-free
            float4 av1 = ld4(&As[k][ty * 4 + 64]);
            float4 bv0 = ld4(&Bs[k][tx * 4]);        // 2-way (tx vs tx+8): free
            float4 bv1 = ld4(&Bs[k][tx * 4 + 64]);
            const float am[8] = {av0.x, av0.y, av0.z, av0.w,
                                 av1.x, av1.y, av1.z, av1.w};
            const float bn8[8] = {bv0.x, bv0.y, bv0.z, bv0.w,
                                  bv1.x, bv1.y, bv1.z, bv1.w};
#pragma unroll
            for (int i = 0; i < 8; ++i)
#pragma unroll
                for (int j = 0; j < 8; ++j)
                    acc[i][j] = fmaf(am[i], bn8[j], acc[i][j]);
        }
        __syncthreads();
    }

    // epilogue: + bias (zeros -> exact), coalesced float4 stores
    float4 bb0 = ld4(&bias[n0 + tx * 4]);
    float4 bb1 = ld4(&bias[n0 + tx * 4 + 64]);
#pragma unroll
    for (int i = 0; i < 8; ++i) {
        const int r = m0 + ((i < 4) ? (ty * 4 + i) : (64 + ty * 4 + (i - 4)));
        float4 o0, o1;
        o0.x = acc[i][0] + bb0.x;  o0.y = acc[i][1] + bb0.y;
        o0.z = acc[i][2] + bb0.z;  o0.w = acc[i][3] + bb0.w;
        o1.x = acc[i][4] + bb1.x;  o1.y = acc[i][5] + bb1.y;
        o1.z = acc[i][6] + bb1.z;  o1.w = acc[i][7] + bb1.w;
        *reinterpret_cast<float4*>(&Hout[(size_t)r * H_ + n0 + tx * 4])      = o0;
        *reinterpret_cast<float4*>(&Hout[(size_t)r * H_ + n0 + tx * 4 + 64]) = o1;
    }

    if (flags) {
        __threadfence();            // each thread's h-stores device-visible
        __syncthreads();            // ... before tid0 signals
        if (tid == 0)
            __hip_atomic_fetch_add(&flags[tau], 1, __ATOMIC_RELEASE,
                                   __HIP_MEMORY_SCOPE_AGENT);
    }
}

// ---------------------------------------------------------------------------
// Scan body: one thread per (b,h) chain, T=2048 steps. Arithmetic statements
// are VERBATIM from the passing Round-3 kernel (bit-exact vs np ref) — do not
// touch. Depth-16 register prefetch inside each 128-step chunk; in fused mode
// tid0 acquire-spins on the chunk's done-flag before the chunk's loads.
// ---------------------------------------------------------------------------
__device__ __forceinline__
void scan_body(const float* __restrict__ Hbuf, float* __restrict__ spikes,
               float* __restrict__ vout, float* __restrict__ thout,
               int sb, int* flags)
{
    const int tid = threadIdx.x;
    const int gid = sb * 256 + tid;       // 0..8191
    const int b = gid >> 9;
    const int h = gid & 511;

    const float* ip = Hbuf   + (size_t)b * T_ * H_ + h;
    float*       sp = spikes + (size_t)b * T_ * H_ + h;

    const float DECAY_F = 0.9048374180359595f;  // exp(-1/10)
    const float ALPHA_F = 0.01f;

    float v = 0.0f, theta = 1.0f;

    for (int tau = 0; tau < NTAU; ++tau) {
        if (flags) {
            if (tid == 0) {
                while (__hip_atomic_load(&flags[tau], __ATOMIC_ACQUIRE,
                                         __HIP_MEMORY_SCOPE_AGENT) < BLOCKS_PER_TAU)
                    __builtin_amdgcn_s_sleep(8);
            }
            __syncthreads();
        }
        const int tb = tau * TCHUNK;

        float buf[16];
#pragma unroll
        for (int j = 0; j < 16; ++j) buf[j] = ip[(size_t)(tb + j) * H_];

        for (int t0 = 0; t0 < TCHUNK; t0 += 16) {
            float nbuf[16];
            if (t0 + 16 < TCHUNK) {
#pragma unroll
                for (int j = 0; j < 16; ++j)
                    nbuf[j] = ip[(size_t)(tb + t0 + 16 + j) * H_];
            }
#pragma unroll
            for (int j = 0; j < 16; ++j) {
                float cur = buf[j];
                v = v * DECAY_F + cur;
                float cl = 32.0f * theta;                  // L * theta * 2
                v = fminf(fmaxf(v, -cl), cl);
                float s = floorf(v / theta);               // IEEE div
                s = fminf(fmaxf(s, 0.0f), 16.0f);
                v = v - s * theta;
                theta = theta + ALPHA_F * s - ALPHA_F * (theta - 1.0f);
                sp[(size_t)(tb + t0 + j) * H_] = s;
            }
#pragma unroll
            for (int j = 0; j < 16; ++j) buf[j] = nbuf[j];
        }
    }
    vout[gid]  = v;
    thout[gid] = theta;
}

// ---------------------------------------------------------------------------
__global__ __launch_bounds__(256)
void fused_kernel(const float* __restrict__ X, const float* __restrict__ W,
                  const float* __restrict__ bias, float* __restrict__ hbuf,
                  float* __restrict__ spikes, float* __restrict__ vf,
                  float* __restrict__ thf, int* flags)
{
    // scan blocks first -> resident early; GEMM blocks ordered by tau so
    // chunk 0 completes first. Scan never blocks GEMM -> no deadlock.
    if ((int)blockIdx.x < SCAN_BLOCKS)
        scan_body(hbuf, spikes, vf, thf, blockIdx.x, flags);
    else
        gemm_body(X, W, bias, hbuf, blockIdx.x - SCAN_BLOCKS, flags);
}

__global__ __launch_bounds__(256)
void gemm_kernel(const float* __restrict__ X, const float* __restrict__ W,
                 const float* __restrict__ bias, float* __restrict__ hbuf)
{
    gemm_body(X, W, bias, hbuf, blockIdx.x, nullptr);
}

__global__ __launch_bounds__(256)
void scan_kernel(const float* __restrict__ hbuf, float* __restrict__ spikes,
                 float* __restrict__ vf, float* __restrict__ thf)
{
    scan_body(hbuf, spikes, vf, thf, blockIdx.x, nullptr);
}

// ---------------------------------------------------------------------------
extern "C" void kernel_launch(void* const* d_in, const int* in_sizes, int n_in,
                              void* d_out, int out_size, void* d_ws, size_t ws_size,
                              hipStream_t stream) {
    const float* x    = (const float*)d_in[0];   // [16, 2048, 512]
    const float* W    = (const float*)d_in[1];   // [512, 512]
    const float* bias = (const float*)d_in[2];   // [512]

    float* out    = (float*)d_out;
    float* spikes = out;
    float* v_f    = out + (size_t)M_ * H_;
    float* th_f   = v_f + (size_t)B_ * H_;

    float* hbuf   = (float*)d_ws;
    const size_t hbytes = (size_t)M_ * H_ * sizeof(float);   // 64 MiB

    if (ws_size >= hbytes + 256) {
        // fused producer-consumer path
        int* flags = (int*)((char*)d_ws + hbytes);
        hipMemsetAsync(flags, 0, NTAU * sizeof(int), stream);
        fused_kernel<<<SCAN_BLOCKS + GEMM_BLOCKS, 256, 0, stream>>>(
            x, W, bias, hbuf, spikes, v_f, th_f, flags);
    } else {
        // fallback: two serialized kernels (same bodies, no flags)
        gemm_kernel<<<GEMM_BLOCKS, 256, 0, stream>>>(x, W, bias, hbuf);
        scan_kernel<<<SCAN_BLOCKS, 256, 0, stream>>>(hbuf, spikes, v_f, th_f);
    }
}

// Round 5
// 408.452 us; speedup vs baseline: 1.1826x; 1.1826x over previous
//
#include <hip/hip_runtime.h>

// Problem constants (from reference)
#define B_  16
#define T_  2048
#define IN_ 512
#define H_  512
#define M_  (B_ * T_)

// GEMM tiling
#define BM 128
#define BN 128
#define BK 16
#define LDT (BM + 4)     // pad: staging stores 2-way (free), compute reads conflict-free

static __device__ __forceinline__ float4 ld4(const float* p) {
    return *reinterpret_cast<const float4*>(p);
}

// ---------------------------------------------------------------------------
// Kernel 1: h[m][n] = sum_k x[m][k]*W[n][k] + b[n], fp32 VALU.
// k accumulated strictly in order 0..511 with fmaf -> bit-matches np ref
// (absmax 0.0 in R2/R3/R4). DO NOT reorder the k loop.
// 8x8 micro-tile in 4+4 split (rows ty*4 / ty*4+64, cols tx*4 / tx*4+64):
// LDS compute reads are <=2-way bank-aliased (free, m136). Staging loads are
// register-double-buffered across k-tiles.
// ---------------------------------------------------------------------------
__global__ __launch_bounds__(256)
void gemm_xwT(const float* __restrict__ X, const float* __restrict__ W,
              const float* __restrict__ bias, float* __restrict__ Hout) {
    __shared__ float As[BK][LDT];
    __shared__ float Bs[BK][LDT];

    const int tid = threadIdx.x;
    const int m0  = blockIdx.x * BM;   // 256 m-tiles
    const int n0  = blockIdx.y * BN;   // 4 n-tiles

    const int tx = tid & 15;           // col group
    const int ty = tid >> 4;           // row group

    // staging: row = tid>>2 (0..63), kph = (tid&3)*4 -> coalesced float4 loads
    const int row = tid >> 2;
    const int kph = (tid & 3) * 4;

    const float* pa0 = X + (size_t)(m0 + row) * IN_ + kph;
    const float* pa1 = pa0 + (size_t)64 * IN_;
    const float* pb0 = W + (size_t)(n0 + row) * IN_ + kph;
    const float* pb1 = pb0 + (size_t)64 * IN_;

    float4 ra0 = ld4(pa0), ra1 = ld4(pa1), rb0 = ld4(pb0), rb1 = ld4(pb1);

    float acc[8][8];
#pragma unroll
    for (int i = 0; i < 8; ++i)
#pragma unroll
        for (int j = 0; j < 8; ++j) acc[i][j] = 0.0f;

    for (int k0 = 0; k0 < IN_; k0 += BK) {
        As[kph + 0][row]      = ra0.x;  As[kph + 1][row]      = ra0.y;
        As[kph + 2][row]      = ra0.z;  As[kph + 3][row]      = ra0.w;
        As[kph + 0][row + 64] = ra1.x;  As[kph + 1][row + 64] = ra1.y;
        As[kph + 2][row + 64] = ra1.z;  As[kph + 3][row + 64] = ra1.w;
        Bs[kph + 0][row]      = rb0.x;  Bs[kph + 1][row]      = rb0.y;
        Bs[kph + 2][row]      = rb0.z;  Bs[kph + 3][row]      = rb0.w;
        Bs[kph + 0][row + 64] = rb1.x;  Bs[kph + 1][row + 64] = rb1.y;
        Bs[kph + 2][row + 64] = rb1.z;  Bs[kph + 3][row + 64] = rb1.w;
        __syncthreads();

        // prefetch next k-tile into registers; drains during the 16-k compute
        if (k0 + BK < IN_) {
            ra0 = ld4(pa0 + k0 + BK);  ra1 = ld4(pa1 + k0 + BK);
            rb0 = ld4(pb0 + k0 + BK);  rb1 = ld4(pb1 + k0 + BK);
        }

#pragma unroll
        for (int k = 0; k < BK; ++k) {
            float4 av0 = ld4(&As[k][ty * 4]);
            float4 av1 = ld4(&As[k][ty * 4 + 64]);
            float4 bv0 = ld4(&Bs[k][tx * 4]);
            float4 bv1 = ld4(&Bs[k][tx * 4 + 64]);
            const float am[8] = {av0.x, av0.y, av0.z, av0.w,
                                 av1.x, av1.y, av1.z, av1.w};
            const float bn8[8] = {bv0.x, bv0.y, bv0.z, bv0.w,
                                  bv1.x, bv1.y, bv1.z, bv1.w};
#pragma unroll
            for (int i = 0; i < 8; ++i)
#pragma unroll
                for (int j = 0; j < 8; ++j)
                    acc[i][j] = fmaf(am[i], bn8[j], acc[i][j]);
        }
        __syncthreads();
    }

    // epilogue: + bias (bias is zeros -> exact), coalesced float4 stores
    float4 bb0 = ld4(&bias[n0 + tx * 4]);
    float4 bb1 = ld4(&bias[n0 + tx * 4 + 64]);
#pragma unroll
    for (int i = 0; i < 8; ++i) {
        const int r = m0 + ((i < 4) ? (ty * 4 + i) : (64 + ty * 4 + (i - 4)));
        float4 o0, o1;
        o0.x = acc[i][0] + bb0.x;  o0.y = acc[i][1] + bb0.y;
        o0.z = acc[i][2] + bb0.z;  o0.w = acc[i][3] + bb0.w;
        o1.x = acc[i][4] + bb1.x;  o1.y = acc[i][5] + bb1.y;
        o1.z = acc[i][6] + bb1.z;  o1.w = acc[i][7] + bb1.w;
        *reinterpret_cast<float4*>(&Hout[(size_t)r * H_ + n0 + tx * 4])      = o0;
        *reinterpret_cast<float4*>(&Hout[(size_t)r * H_ + n0 + tx * 4 + 64]) = o1;
    }
}

// ---------------------------------------------------------------------------
// Kernel 2: GIF neuron scan. One thread per (b,h) chain; T=2048 steps.
// Time = 2048 x step-latency (128 waves -> no TLP hiding possible), so the
// only lever is the dependent chain. The IEEE div (div_scale/div_fmas/
// div_fixup w/ VCC hazards + branches) is replaced by a branch-free
// correctly-rounded sequence: v_rcp_f32 + 2x Newton-Raphson + Markstein
// final fma correction. For theta in [1,17), |v|<=544 (all normal, no
// over/underflow in residuals) this is bit-identical to IEEE v/theta,
// so floor() matches the np reference exactly. All other statements are
// VERBATIM from the bit-matching Round-3 kernel.
// ---------------------------------------------------------------------------
#define PF 32

__global__ __launch_bounds__(256)
void gif_scan(const float* __restrict__ Hbuf, float* __restrict__ spikes,
              float* __restrict__ vout, float* __restrict__ thout) {
    const int gid = blockIdx.x * 256 + threadIdx.x;   // 0..8191
    const int b = gid >> 9;
    const int h = gid & 511;

    const float* ip = Hbuf   + (size_t)b * T_ * H_ + h;
    float*       sp = spikes + (size_t)b * T_ * H_ + h;

    const float DECAY_F = 0.9048374180359595f;  // exp(-1/10)
    const float ALPHA_F = 0.01f;

    float buf[PF];
#pragma unroll
    for (int j = 0; j < PF; ++j) buf[j] = ip[(size_t)j * H_];

    float v = 0.0f, theta = 1.0f;
    for (int t0 = 0; t0 < T_; t0 += PF) {
        float nbuf[PF];
        const int tnx = t0 + PF;
        if (tnx < T_) {
#pragma unroll
            for (int j = 0; j < PF; ++j) nbuf[j] = ip[(size_t)(tnx + j) * H_];
        }
#pragma unroll
        for (int j = 0; j < PF; ++j) {
            float cur = buf[j];
            v = v * DECAY_F + cur;
            float cl = 32.0f * theta;                  // L * theta * 2
            v = fminf(fmaxf(v, -cl), cl);

            // ---- correctly-rounded v/theta (bit-identical to IEEE div) ----
            float r0 = __builtin_amdgcn_rcpf(theta);   // ~1 ulp
            float e0 = fmaf(-theta, r0, 1.0f);
            float r1 = fmaf(r0, e0, r0);               // N-R 1
            float e1 = fmaf(-theta, r1, 1.0f);
            float r2 = fmaf(r1, e1, r1);               // N-R 2: ~0.5 ulp recip
            float q0 = v * r2;
            float er = fmaf(-theta, q0, v);            // exact residual
            float q  = fmaf(er, r2, q0);               // Markstein: correctly rounded
            // ---------------------------------------------------------------

            float s = floorf(q);
            s = fminf(fmaxf(s, 0.0f), 16.0f);
            v = v - s * theta;
            theta = theta + ALPHA_F * s - ALPHA_F * (theta - 1.0f);
            sp[(size_t)(t0 + j) * H_] = s;
        }
#pragma unroll
        for (int j = 0; j < PF; ++j) buf[j] = nbuf[j];
    }
    vout[gid]  = v;
    thout[gid] = theta;
}

// ---------------------------------------------------------------------------
extern "C" void kernel_launch(void* const* d_in, const int* in_sizes, int n_in,
                              void* d_out, int out_size, void* d_ws, size_t ws_size,
                              hipStream_t stream) {
    const float* x    = (const float*)d_in[0];   // [16, 2048, 512]
    const float* W    = (const float*)d_in[1];   // [512, 512]
    const float* bias = (const float*)d_in[2];   // [512]

    float* out    = (float*)d_out;
    float* spikes = out;
    float* v_f    = out + (size_t)M_ * H_;
    float* th_f   = v_f + (size_t)B_ * H_;

    float* hbuf   = (float*)d_ws;                // 64 MiB scratch for h

    dim3 grid(M_ / BM, H_ / BN);                 // 256 x 4
    gemm_xwT<<<grid, 256, 0, stream>>>(x, W, bias, hbuf);
    gif_scan<<<(B_ * H_) / 256, 256, 0, stream>>>(hbuf, spikes, v_f, th_f);
}